// Round 7
// baseline (918.259 us; speedup 1.0000x reference)
//
#include <hip/hip_runtime.h>

// Exphormer attention, fp32, atomic-free via on-device dst-CSR.
// Pipeline per call:
//   memset(cnt) -> proj -> hist -> scan(+cursor) -> scatter(perm) -> agg
// agg: one wave per dst node, register accumulation, single plain store.

// ---------------- Kernel 1: fused Q/K/V projection ----------------
// Qb[node*64+d]; K/V interleaved: KV[node*128 + d] (K), KV[node*128+64+d] (V)
__global__ __launch_bounds__(256) void proj_kernel(
    const float* __restrict__ x,
    const float* __restrict__ Wq, const float* __restrict__ bq,
    const float* __restrict__ Wk, const float* __restrict__ bk,
    const float* __restrict__ Wv, const float* __restrict__ bv,
    float* __restrict__ Qb, float* __restrict__ KV,
    int n)
{
    __shared__ float WqT[64 * 65];
    __shared__ float WkT[64 * 65];
    __shared__ float WvT[64 * 65];
    __shared__ float xs[4][4][64];

    const int tid  = threadIdx.x;
    const int wave = tid >> 6;
    const int lane = tid & 63;

    #pragma unroll
    for (int k = 0; k < 16; ++k) {
        int idx = tid + k * 256;
        int j = idx >> 6, i = idx & 63;
        WqT[i * 65 + j] = Wq[idx];
        WkT[i * 65 + j] = Wk[idx];
        WvT[i * 65 + j] = Wv[idx];
    }
    const float bqv = bq[lane];
    const float bkv = bk[lane];
    const float bvv = bv[lane];
    __syncthreads();

    for (int blockbase = blockIdx.x * 16; blockbase < n;
         blockbase += gridDim.x * 16) {
        int base = blockbase + wave * 4;
        #pragma unroll
        for (int j = 0; j < 4; ++j) {
            int node = base + j;
            xs[wave][j][lane] = (node < n) ? x[node * 64 + lane] : 0.f;
        }
        __syncthreads();

        float accq[4], acck[4], accv[4];
        #pragma unroll
        for (int j = 0; j < 4; ++j) { accq[j] = bqv; acck[j] = bkv; accv[j] = bvv; }

        #pragma unroll
        for (int f = 0; f < 16; ++f) {
            float wq[4], wk[4], wv[4];
            #pragma unroll
            for (int u = 0; u < 4; ++u) {
                int i = 4 * f + u;
                wq[u] = WqT[i * 65 + lane];
                wk[u] = WkT[i * 65 + lane];
                wv[u] = WvT[i * 65 + lane];
            }
            #pragma unroll
            for (int j = 0; j < 4; ++j) {
                float4 xv = *reinterpret_cast<const float4*>(&xs[wave][j][4 * f]);
                accq[j] = fmaf(xv.x, wq[0], accq[j]);
                accq[j] = fmaf(xv.y, wq[1], accq[j]);
                accq[j] = fmaf(xv.z, wq[2], accq[j]);
                accq[j] = fmaf(xv.w, wq[3], accq[j]);
                acck[j] = fmaf(xv.x, wk[0], acck[j]);
                acck[j] = fmaf(xv.y, wk[1], acck[j]);
                acck[j] = fmaf(xv.z, wk[2], acck[j]);
                acck[j] = fmaf(xv.w, wk[3], acck[j]);
                accv[j] = fmaf(xv.x, wv[0], accv[j]);
                accv[j] = fmaf(xv.y, wv[1], accv[j]);
                accv[j] = fmaf(xv.z, wv[2], accv[j]);
                accv[j] = fmaf(xv.w, wv[3], accv[j]);
            }
        }

        #pragma unroll
        for (int j = 0; j < 4; ++j) {
            int node = base + j;
            if (node < n) {
                Qb[(size_t)node * 64 + lane]       = accq[j];
                KV[(size_t)node * 128 + lane]      = acck[j];
                KV[(size_t)node * 128 + 64 + lane] = accv[j];
            }
        }
        __syncthreads();
    }
}

// ---------------- Kernel 2: histogram of dst ----------------
__global__ __launch_bounds__(256) void hist_kernel(
    const int* __restrict__ ei, int* __restrict__ cnt, int EG)
{
    int i  = blockIdx.x * blockDim.x + threadIdx.x;
    int st = gridDim.x * blockDim.x;
    for (int e = i; e < EG; e += st)
        atomicAdd(&cnt[ei[EG + e]], 1);
}

// ---------------- Kernel 3: single-block exclusive scan ----------------
// off[i] = sum_{k<i} cnt[k]; off[n] = total; cursor = copy of off[0..n)
__global__ __launch_bounds__(1024) void scan_kernel(
    const int* __restrict__ cnt, int* __restrict__ off,
    int* __restrict__ cursor, int n, int C)
{
    __shared__ int part[1024];
    const int t  = threadIdx.x;
    const int c0 = t * C;
    const int hi = min(c0 + C, n);

    int s = 0;
    for (int i = c0; i < hi; ++i) s += cnt[i];
    part[t] = s;
    __syncthreads();

    for (int d = 1; d < 1024; d <<= 1) {   // Hillis-Steele inclusive scan
        int v = (t >= d) ? part[t - d] : 0;
        __syncthreads();
        part[t] += v;
        __syncthreads();
    }

    int pre = (t == 0) ? 0 : part[t - 1];
    for (int i = c0; i < hi; ++i) {
        off[i] = pre;
        cursor[i] = pre;
        pre += cnt[i];
    }
    if (t == 1023) off[n] = part[1023];
}

// ---------------- Kernel 4: scatter edge ids into dst-grouped perm ----------------
__global__ __launch_bounds__(256) void scatter_kernel(
    const int* __restrict__ ei, int* __restrict__ cursor,
    int* __restrict__ perm, int EG)
{
    int i  = blockIdx.x * blockDim.x + threadIdx.x;
    int st = gridDim.x * blockDim.x;
    for (int e = i; e < EG; e += st) {
        int d = ei[EG + e];
        int p = atomicAdd(&cursor[d], 1);
        perm[p] = e;
    }
}

// ---------------- Kernel 5: per-dst aggregation (atomic-free) ----------------
// 4 independent waves/block; wave <-> dst node; lane <-> output dim.
// Edge list walked serially with R4-proven prefetch (indices 2-ahead,
// data 1-ahead). We row pinned in 64 regs via empty-asm. Single store/dst.
__global__ __launch_bounds__(256, 4) void agg_kernel(
    const float* __restrict__ ea, const int* __restrict__ ei,
    const int* __restrict__ off, const int* __restrict__ perm,
    const float* __restrict__ Qb, const float* __restrict__ KV,
    const float* __restrict__ We, const float* __restrict__ be,
    float* __restrict__ out, int n, int EG)
{
    __shared__ float eas[4][64];

    const int tid  = threadIdx.x;
    const int wave = tid >> 6;
    const int lane = tid & 63;

    float wr[64];
    {
        const float4* wrow = reinterpret_cast<const float4*>(We + (size_t)lane * 64);
        #pragma unroll
        for (int f = 0; f < 16; ++f) {
            float4 t4 = wrow[f];
            wr[4 * f + 0] = t4.x;
            wr[4 * f + 1] = t4.y;
            wr[4 * f + 2] = t4.z;
            wr[4 * f + 3] = t4.w;
        }
    }
    #pragma unroll
    for (int i = 0; i < 64; ++i)
        asm volatile("" : "+v"(wr[i]));   // opaque: cannot be rematerialized
    const float bias = be[lane];

    const int nw  = gridDim.x * 4;
    const int wid = blockIdx.x * 4 + __builtin_amdgcn_readfirstlane(wave);

    for (int d = wid; d < n; d += nw) {
        const int j0 = off[d];
        const int j1 = off[d + 1];
        const float qv = Qb[(size_t)d * 64 + lane];
        float acc = 0.f;

        if (j0 < j1) {
            // prologue
            int e0 = perm[j0];
            int s0 = ei[e0];
            float eav = ea[(size_t)e0 * 64 + lane];
            float kv  = KV[(size_t)s0 * 128 + lane];
            float vv  = KV[(size_t)s0 * 128 + 64 + lane];
            int e1 = 0, s1 = 0;
            if (j0 + 1 < j1) { e1 = perm[j0 + 1]; s1 = ei[e1]; }

            for (int j = j0; j < j1; ++j) {
                // data prefetch for j+1 (addresses ready from last iter)
                float eav_n = 0.f, kv_n = 0.f, vv_n = 0.f;
                if (j + 1 < j1) {
                    eav_n = ea[(size_t)e1 * 64 + lane];
                    kv_n  = KV[(size_t)s1 * 128 + lane];
                    vv_n  = KV[(size_t)s1 * 128 + 64 + lane];
                }
                // index prefetch for j+2
                int e2 = 0, s2 = 0;
                if (j + 2 < j1) { e2 = perm[j + 2]; s2 = ei[e2]; }

                // Ee matvec: LDS broadcast x pinned We regs
                eas[wave][lane] = eav;
                __builtin_amdgcn_wave_barrier();
                float Ee = bias;
                const float4* r4 = reinterpret_cast<const float4*>(eas[wave]);
                #pragma unroll
                for (int f = 0; f < 16; ++f) {
                    float4 a = r4[f];
                    Ee = fmaf(a.x, wr[4 * f + 0], Ee);
                    Ee = fmaf(a.y, wr[4 * f + 1], Ee);
                    Ee = fmaf(a.z, wr[4 * f + 2], Ee);
                    Ee = fmaf(a.w, wr[4 * f + 3], Ee);
                }
                __builtin_amdgcn_wave_barrier();   // eas reused next iter

                // score over 16-lane head group, accumulate message
                float t = kv * qv * 0.25f * Ee;
                t += __shfl_xor(t, 1);
                t += __shfl_xor(t, 2);
                t += __shfl_xor(t, 4);
                t += __shfl_xor(t, 8);
                t = fminf(fmaxf(t, -5.f), 5.f);
                acc = fmaf(vv, __expf(t), acc);

                // rotate
                eav = eav_n; kv = kv_n; vv = vv_n;
                e1 = e2; s1 = s2;
            }
        }
        out[(size_t)d * 64 + lane] = acc;   // plain coalesced store
    }
}

extern "C" void kernel_launch(void* const* d_in, const int* in_sizes, int n_in,
                              void* d_out, int out_size, void* d_ws, size_t ws_size,
                              hipStream_t stream) {
    const float* x   = (const float*)d_in[0];
    const float* ea  = (const float*)d_in[1];
    const int*   ei  = (const int*)d_in[2];
    const float* Wq  = (const float*)d_in[3];
    const float* bq  = (const float*)d_in[4];
    const float* Wk  = (const float*)d_in[5];
    const float* bk  = (const float*)d_in[6];
    const float* We  = (const float*)d_in[7];
    const float* be  = (const float*)d_in[8];
    const float* Wv  = (const float*)d_in[9];
    const float* bv  = (const float*)d_in[10];
    float* out = (float*)d_out;

    const int n  = in_sizes[0] / 64;   // 50000
    const int EG = in_sizes[1] / 64;   // 1600000

    // workspace layout (floats/ints, all 4B aligned):
    float* Qb   = (float*)d_ws;                 // n*64
    float* KV   = Qb + (size_t)n * 64;          // n*128
    int* cnt    = (int*)(KV + (size_t)n * 128); // n
    int* off    = cnt + n;                      // n+1
    int* cursor = off + n + 1;                  // n
    int* perm   = cursor + n;                   // EG

    hipMemsetAsync(cnt, 0, (size_t)n * sizeof(int), stream);

    const int projGrid = (n + 15) / 16;
    proj_kernel<<<projGrid, 256, 0, stream>>>(x, Wq, bq, Wk, bk, Wv, bv,
                                              Qb, KV, n);

    hist_kernel<<<2048, 256, 0, stream>>>(ei, cnt, EG);

    const int C = (n + 1023) / 1024;
    scan_kernel<<<1, 1024, 0, stream>>>(cnt, off, cursor, n, C);

    scatter_kernel<<<2048, 256, 0, stream>>>(ei, cursor, perm, EG);

    const int aggGrid = (n + 3) / 4;
    agg_kernel<<<aggGrid, 256, 0, stream>>>(ea, ei, off, perm,
                                            Qb, KV, We, be, out, n, EG);
}

// Round 8
// 503.276 us; speedup vs baseline: 1.8246x; 1.8246x over previous
//
#include <hip/hip_runtime.h>

// Exphormer attention, fp32 accuracy via split-bf16 MFMA, 16-edge tiles.
// out[dst] += V[src] * exp(clip(sum_d K[src,h,d]*Q[dst,h,d]/4 * Ee[e,h,d], ±5))
// Ee = edge_attr @ We^T + be  (Veltkamp split: hi*hi + hi*lo + lo*hi)
//
// Per 16-edge tile (one wave):
//   phase A: ea -> A frags (global, fragment layout) ; B frags from LDS
//            24 x mfma_f32_16x16x32_bf16 -> Ee tile ; transpose via LDS
//   phase B: per edge r: Ee row from LDS (lane=dim), K/V/Q gathers coalesced
//            256B with SGPR base (indices s_loaded), shfl-reduce score,
//            exp, atomic scatter.

typedef __attribute__((ext_vector_type(8))) short bf16x8;   // MFMA A/B frag
typedef __attribute__((ext_vector_type(4))) float f32x4;    // MFMA C/D frag

union frag_u { uint32_t u[4]; uint4 u4; bf16x8 v; };

// pack two f32 (truncated to bf16) into one dword; a -> low half (lower k)
__device__ __forceinline__ uint32_t pack2(float a, float b) {
    return (__float_as_uint(a) >> 16) | (__float_as_uint(b) & 0xffff0000u);
}

// float4 -> 2 hi dwords + 2 lo dwords (bf16 pairs). hi truncate, lo = x-hi exact.
__device__ __forceinline__ void cvt4(float4 v, uint32_t& h0, uint32_t& h1,
                                     uint32_t& l0, uint32_t& l1) {
    float hx = __uint_as_float(__float_as_uint(v.x) & 0xffff0000u);
    float hy = __uint_as_float(__float_as_uint(v.y) & 0xffff0000u);
    float hz = __uint_as_float(__float_as_uint(v.z) & 0xffff0000u);
    float hw = __uint_as_float(__float_as_uint(v.w) & 0xffff0000u);
    h0 = pack2(v.x, v.y);
    h1 = pack2(v.z, v.w);
    l0 = pack2(v.x - hx, v.y - hy);
    l1 = pack2(v.z - hz, v.w - hw);
}

// ---------------- Kernel 1: fused Q/K/V projection ----------------
// Qb[node*64+d]; K/V interleaved: KV[node*128 + d] (K), KV[node*128+64+d] (V)
__global__ __launch_bounds__(256) void proj_kernel(
    const float* __restrict__ x,
    const float* __restrict__ Wq, const float* __restrict__ bq,
    const float* __restrict__ Wk, const float* __restrict__ bk,
    const float* __restrict__ Wv, const float* __restrict__ bv,
    float* __restrict__ Qb, float* __restrict__ KV,
    int n)
{
    __shared__ float WqT[64 * 65];
    __shared__ float WkT[64 * 65];
    __shared__ float WvT[64 * 65];
    __shared__ float xs[4][4][64];

    const int tid  = threadIdx.x;
    const int wave = tid >> 6;
    const int lane = tid & 63;

    #pragma unroll
    for (int k = 0; k < 16; ++k) {
        int idx = tid + k * 256;
        int j = idx >> 6, i = idx & 63;
        WqT[i * 65 + j] = Wq[idx];
        WkT[i * 65 + j] = Wk[idx];
        WvT[i * 65 + j] = Wv[idx];
    }
    const float bqv = bq[lane];
    const float bkv = bk[lane];
    const float bvv = bv[lane];
    __syncthreads();

    for (int blockbase = blockIdx.x * 16; blockbase < n;
         blockbase += gridDim.x * 16) {
        int base = blockbase + wave * 4;
        #pragma unroll
        for (int j = 0; j < 4; ++j) {
            int node = base + j;
            xs[wave][j][lane] = (node < n) ? x[node * 64 + lane] : 0.f;
        }
        __syncthreads();

        float accq[4], acck[4], accv[4];
        #pragma unroll
        for (int j = 0; j < 4; ++j) { accq[j] = bqv; acck[j] = bkv; accv[j] = bvv; }

        #pragma unroll
        for (int f = 0; f < 16; ++f) {
            float wq[4], wk[4], wv[4];
            #pragma unroll
            for (int u = 0; u < 4; ++u) {
                int i = 4 * f + u;
                wq[u] = WqT[i * 65 + lane];
                wk[u] = WkT[i * 65 + lane];
                wv[u] = WvT[i * 65 + lane];
            }
            #pragma unroll
            for (int j = 0; j < 4; ++j) {
                float4 xv = *reinterpret_cast<const float4*>(&xs[wave][j][4 * f]);
                accq[j] = fmaf(xv.x, wq[0], accq[j]);
                accq[j] = fmaf(xv.y, wq[1], accq[j]);
                accq[j] = fmaf(xv.z, wq[2], accq[j]);
                accq[j] = fmaf(xv.w, wq[3], accq[j]);
                acck[j] = fmaf(xv.x, wk[0], acck[j]);
                acck[j] = fmaf(xv.y, wk[1], acck[j]);
                acck[j] = fmaf(xv.z, wk[2], acck[j]);
                acck[j] = fmaf(xv.w, wk[3], acck[j]);
                accv[j] = fmaf(xv.x, wv[0], accv[j]);
                accv[j] = fmaf(xv.y, wv[1], accv[j]);
                accv[j] = fmaf(xv.z, wv[2], accv[j]);
                accv[j] = fmaf(xv.w, wv[3], accv[j]);
            }
        }

        #pragma unroll
        for (int j = 0; j < 4; ++j) {
            int node = base + j;
            if (node < n) {
                Qb[(size_t)node * 64 + lane]       = accq[j];
                KV[(size_t)node * 128 + lane]      = acck[j];
                KV[(size_t)node * 128 + 64 + lane] = accv[j];
            }
        }
        __syncthreads();
    }
}

// ---------------- Kernel 2: 16-edge-tile MFMA attention ----------------
// Fragment layouts (gfx950 16x16x32 bf16, verified by R6 passing):
//   A: lane(q=l&15,g=l>>4): row m=q (edge), k = 32ks + 16b + 4g + j
//   B: lane:                col n=q (dim),  k = 32ks + 16b + 4g + j
//   C: lane:                col n=q (dim),  row = 4g + reg (edge)
__global__ __launch_bounds__(256) void edge_kernel(
    const float* __restrict__ ea, const int* __restrict__ ei,
    const float* __restrict__ Qb, const float* __restrict__ KV,
    const float* __restrict__ We, const float* __restrict__ be,
    float* __restrict__ out, int EG)   // EG % 16 == 0
{
    __shared__ uint4 bfragLDS[16][64];   // [(nt*2+ks)*2+hl][lane], 16 KB
    __shared__ float els[4][16][66];     // per-wave Ee tile, +2 pad: <=2-way banks

    const int tid  = threadIdx.x;
    const int wave = __builtin_amdgcn_readfirstlane(tid >> 6);
    const int lane = tid & 63;
    const int g    = lane >> 4;
    const int q    = lane & 15;

    // ---- build B fragments cooperatively: wave w handles nt = w ----
    {
        const int nt = wave;
        #pragma unroll
        for (int ks = 0; ks < 2; ++ks) {
            frag_u fh, fl;
            #pragma unroll
            for (int b = 0; b < 2; ++b) {
                float4 w4 = *reinterpret_cast<const float4*>(
                    &We[(size_t)(16 * nt + q) * 64 + 32 * ks + 16 * b + 4 * g]);
                cvt4(w4, fh.u[2 * b + 0], fh.u[2 * b + 1],
                         fl.u[2 * b + 0], fl.u[2 * b + 1]);
            }
            bfragLDS[nt * 4 + ks * 2 + 0][lane] = fh.u4;
            bfragLDS[nt * 4 + ks * 2 + 1][lane] = fl.u4;
        }
    }
    float bias4[4];
    #pragma unroll
    for (int nt = 0; nt < 4; ++nt) bias4[nt] = be[16 * nt + q];
    __syncthreads();   // bfragLDS read-only afterwards

    const int nw  = gridDim.x * 4;
    const int wid = blockIdx.x * 4 + wave;

    for (int eb = wid * 16; eb < EG; eb += nw * 16) {   // eb wave-uniform
        // ---- edge indices: uniform address -> s_load_dwordx16 ----
        int srcs[16], dsts[16];
        #pragma unroll
        for (int r = 0; r < 16; ++r) {
            srcs[r] = ei[eb + r];
            dsts[r] = ei[EG + eb + r];
        }

        // ---- A fragments from global (row m=q -> edge eb+q) ----
        frag_u Ah[2], Al[2];
        const float* arow = &ea[(size_t)(eb + q) * 64];
        #pragma unroll
        for (int ks = 0; ks < 2; ++ks) {
            #pragma unroll
            for (int b = 0; b < 2; ++b) {
                float4 a4 = *reinterpret_cast<const float4*>(
                    &arow[32 * ks + 16 * b + 4 * g]);
                cvt4(a4, Ah[ks].u[2 * b + 0], Ah[ks].u[2 * b + 1],
                         Al[ks].u[2 * b + 0], Al[ks].u[2 * b + 1]);
            }
        }

        // ---- Ee = ea @ We^T + be via split-bf16 MFMA ----
        f32x4 acc[4];
        #pragma unroll
        for (int nt = 0; nt < 4; ++nt) {
            acc[nt][0] = bias4[nt]; acc[nt][1] = bias4[nt];
            acc[nt][2] = bias4[nt]; acc[nt][3] = bias4[nt];
            #pragma unroll
            for (int ks = 0; ks < 2; ++ks) {
                frag_u bh, bl;
                bh.u4 = bfragLDS[nt * 4 + ks * 2 + 0][lane];
                bl.u4 = bfragLDS[nt * 4 + ks * 2 + 1][lane];
                acc[nt] = __builtin_amdgcn_mfma_f32_16x16x32_bf16(
                              Al[ks].v, bh.v, acc[nt], 0, 0, 0);
                acc[nt] = __builtin_amdgcn_mfma_f32_16x16x32_bf16(
                              Ah[ks].v, bl.v, acc[nt], 0, 0, 0);
                acc[nt] = __builtin_amdgcn_mfma_f32_16x16x32_bf16(
                              Ah[ks].v, bh.v, acc[nt], 0, 0, 0);
            }
        }

        // ---- transpose Ee via LDS: els[wave][edge r][dim] ----
        #pragma unroll
        for (int nt = 0; nt < 4; ++nt) {
            #pragma unroll
            for (int r = 0; r < 4; ++r)
                els[wave][4 * g + r][16 * nt + q] = acc[nt][r];
        }
        __builtin_amdgcn_wave_barrier();   // writes before reads (lgkmcnt auto)

        // ---- phase B: per edge, coalesced gathers + score + scatter ----
        #pragma unroll
        for (int r = 0; r < 16; ++r) {
            const float Ee = els[wave][r][lane];          // 2-way banks: free
            const float* kb = KV + (size_t)srcs[r] * 128; // SGPR base
            const float kv = kb[lane];
            const float vv = kb[64 + lane];
            const float qv = Qb[(size_t)dsts[r] * 64 + lane];
            float t = kv * qv * 0.25f * Ee;
            t += __shfl_xor(t, 1);
            t += __shfl_xor(t, 2);
            t += __shfl_xor(t, 4);
            t += __shfl_xor(t, 8);
            t = fminf(fmaxf(t, -5.f), 5.f);
            float s = __expf(t);
            atomicAdd(&out[(size_t)dsts[r] * 64 + lane], vv * s);
        }
        __builtin_amdgcn_wave_barrier();   // els rewritten next tile
    }
}

extern "C" void kernel_launch(void* const* d_in, const int* in_sizes, int n_in,
                              void* d_out, int out_size, void* d_ws, size_t ws_size,
                              hipStream_t stream) {
    const float* x   = (const float*)d_in[0];
    const float* ea  = (const float*)d_in[1];
    const int*   ei  = (const int*)d_in[2];
    const float* Wq  = (const float*)d_in[3];
    const float* bq  = (const float*)d_in[4];
    const float* Wk  = (const float*)d_in[5];
    const float* bk  = (const float*)d_in[6];
    const float* We  = (const float*)d_in[7];
    const float* be  = (const float*)d_in[8];
    const float* Wv  = (const float*)d_in[9];
    const float* bv  = (const float*)d_in[10];
    float* out = (float*)d_out;

    const int n  = in_sizes[0] / 64;   // 50000
    const int EG = in_sizes[1] / 64;   // 1600000 (divisible by 16)

    float* Qb = (float*)d_ws;                 // n*64
    float* KV = Qb + (size_t)n * 64;          // n*128 (K|V interleaved)

    hipMemsetAsync(d_out, 0, (size_t)out_size * sizeof(float), stream);

    const int projGrid = (n + 15) / 16;
    proj_kernel<<<projGrid, 256, 0, stream>>>(x, Wq, bq, Wk, bk, Wv, bv,
                                              Qb, KV, n);

    // 2500 blocks x 4 waves = 10000 waves; 100000 tiles -> 10 tiles/wave exact
    edge_kernel<<<2500, 256, 0, stream>>>(ea, ei, Qb, KV, We, be, out, EG);
}